// Round 2
// baseline (7949.593 us; speedup 1.0000x reference)
//
#include <hip/hip_runtime.h>
#include <math.h>

#define N 4096
#define D 512
#define L 128
#define PARTS 16
#define PARTJ (N / PARTS)   // 256
#define TI 128
#define TJ 64
#define KD 32
#define AS_STRIDE (TI + 4)  // 132
#define BS_STRIDE (TJ + 4)  // 68
#define DS_STRIDE (TJ + 4)  // 68
// shared pool: distS (TI*DS_STRIDE = 8704 floats = 34 KB) unions with
// As (KD*AS_STRIDE = 4224) + Bs (KD*BS_STRIDE = 2176) = 6400 floats.
#define SMEM_FLOATS (TI * DS_STRIDE)

// Insert v into ascending sorted tk[0..15], dropping the old max.
// Caller guarantees v < tk[15].
__device__ __forceinline__ void topk_insert(float (&tk)[16], float v) {
  float x = v;
#pragma unroll
  for (int k = 0; k < 16; ++k) {
    float lo = fminf(x, tk[k]);
    float hi = fmaxf(x, tk[k]);
    tk[k] = lo;
    x = hi;
  }
}

// rec = latent @ W + b ; grid (N/8, 2), block 256. y==0 -> test, y==1 -> train
__global__ __launch_bounds__(256) void linear_kernel(
    const float* __restrict__ lat_test, const float* __restrict__ lat_train,
    const float* __restrict__ W, const float* __restrict__ bias,
    float* __restrict__ rec_test, float* __restrict__ rec_train) {
  const float* __restrict__ lat = blockIdx.y ? lat_train : lat_test;
  float* __restrict__ out = blockIdx.y ? rec_train : rec_test;
  const int r0 = blockIdx.x * 8;
  const int t = threadIdx.x;

  __shared__ float ls[8 * L];  // 8 latent rows
  {
    float4 v = *(const float4*)(lat + (size_t)r0 * L + t * 4);
    *(float4*)&ls[t * 4] = v;
  }
  __syncthreads();

  float acc[8][2];
#pragma unroll
  for (int r = 0; r < 8; ++r) { acc[r][0] = 0.f; acc[r][1] = 0.f; }

#pragma unroll 4
  for (int l = 0; l < L; ++l) {
    float w0 = W[l * D + t];
    float w1 = W[l * D + t + 256];
#pragma unroll
    for (int r = 0; r < 8; ++r) {
      float x = ls[r * L + l];
      acc[r][0] = fmaf(x, w0, acc[r][0]);
      acc[r][1] = fmaf(x, w1, acc[r][1]);
    }
  }
  float b0 = bias[t], b1 = bias[t + 256];
#pragma unroll
  for (int r = 0; r < 8; ++r) {
    out[(size_t)(r0 + r) * D + t] = acc[r][0] + b0;
    out[(size_t)(r0 + r) * D + t + 256] = acc[r][1] + b1;
  }
}

// Fused L1-cdist + per-row top-16 (smallest distances) over one j-part.
// grid (N/TI, PARTS, 2), block 256. z==0: B=gt_vals, z==1: B=rec_train.
// cand layout: [mat][part][row][16], each 16-list sorted ascending.
__global__ __launch_bounds__(256, 4) void dist_topk_kernel(
    const float* __restrict__ Arec, const float* __restrict__ Bgt,
    const float* __restrict__ Btr, float* __restrict__ cand) {
  const int itile = blockIdx.x;
  const int part = blockIdx.y;
  const int mat = blockIdx.z;
  const float* __restrict__ B = mat ? Btr : Bgt;
  const int i0 = itile * TI;
  const int jbase = part * PARTJ;

  // One pool: As/Bs live only inside the d-loop; distS only after it.
  __shared__ float smem[SMEM_FLOATS];  // 34816 B -> 4 blocks/CU
  float* As = smem;                    // [KD][AS_STRIDE]
  float* Bs = smem + KD * AS_STRIDE;   // [KD][BS_STRIDE]
  float* distS = smem;                 // [TI][DS_STRIDE]

  const int tid = threadIdx.x;
  const int tx = tid & 15;   // j = 4*tx
  const int ty = tid >> 4;   // i = 8*ty

  float tk[16];
#pragma unroll
  for (int k = 0; k < 16; ++k) tk[k] = 3.0e38f;

  for (int jc = 0; jc < PARTJ; jc += TJ) {
    float acc[8][4];
#pragma unroll
    for (int r = 0; r < 8; ++r)
#pragma unroll
      for (int c = 0; c < 4; ++c) acc[r][c] = 0.f;

    for (int d0 = 0; d0 < D; d0 += KD) {
      __syncthreads();  // previous consumers (compute or topk scan) done
      // stage A: TI x KD = 4096 floats, 4 float4 per thread, transposed store
#pragma unroll
      for (int s = 0; s < 4; ++s) {
        int f4 = tid + s * 256;
        int r = f4 >> 3;    // 0..127
        int c4 = f4 & 7;    // float4 within the 32-wide d-chunk
        float4 v = *(const float4*)(Arec + (size_t)(i0 + r) * D + d0 + c4 * 4);
        As[(4 * c4 + 0) * AS_STRIDE + r] = v.x;
        As[(4 * c4 + 1) * AS_STRIDE + r] = v.y;
        As[(4 * c4 + 2) * AS_STRIDE + r] = v.z;
        As[(4 * c4 + 3) * AS_STRIDE + r] = v.w;
      }
      // stage B: TJ x KD = 2048 floats, 2 float4 per thread
#pragma unroll
      for (int s = 0; s < 2; ++s) {
        int f4 = tid + s * 256;
        int r = f4 >> 3;    // 0..63
        int c4 = f4 & 7;
        float4 v = *(const float4*)(B + (size_t)(jbase + jc + r) * D + d0 + c4 * 4);
        Bs[(4 * c4 + 0) * BS_STRIDE + r] = v.x;
        Bs[(4 * c4 + 1) * BS_STRIDE + r] = v.y;
        Bs[(4 * c4 + 2) * BS_STRIDE + r] = v.z;
        Bs[(4 * c4 + 3) * BS_STRIDE + r] = v.w;
      }
      __syncthreads();

#pragma unroll
      for (int d = 0; d < KD; ++d) {
        float4 a0 = *(const float4*)&As[d * AS_STRIDE + 8 * ty];
        float4 a1 = *(const float4*)&As[d * AS_STRIDE + 8 * ty + 4];
        float4 bv4 = *(const float4*)&Bs[d * BS_STRIDE + 4 * tx];
        float av[8] = {a0.x, a0.y, a0.z, a0.w, a1.x, a1.y, a1.z, a1.w};
        float bv[4] = {bv4.x, bv4.y, bv4.z, bv4.w};
#pragma unroll
        for (int r = 0; r < 8; ++r)
#pragma unroll
          for (int c = 0; c < 4; ++c) acc[r][c] += fabsf(av[r] - bv[c]);
      }
    }

    __syncthreads();  // all compute done reading As/Bs before distS overwrite
#pragma unroll
    for (int r = 0; r < 8; ++r)
#pragma unroll
      for (int c = 0; c < 4; ++c)
        distS[(8 * ty + r) * DS_STRIDE + 4 * tx + c] = acc[r][c];
    __syncthreads();

    if (tid < TI) {
#pragma unroll 1
      for (int j4 = 0; j4 < TJ / 4; ++j4) {
        float4 v = *(const float4*)&distS[tid * DS_STRIDE + j4 * 4];
        if (v.x < tk[15]) topk_insert(tk, v.x);
        if (v.y < tk[15]) topk_insert(tk, v.y);
        if (v.z < tk[15]) topk_insert(tk, v.z);
        if (v.w < tk[15]) topk_insert(tk, v.w);
      }
    }
    // loop-top __syncthreads protects distS from next chunk's As/Bs staging
  }

  if (tid < TI) {
    const int row = i0 + tid;
    float* dst = cand + ((size_t)((mat * PARTS + part) * N) + row) * 16;
#pragma unroll
    for (int k = 0; k < 16; ++k) dst[k] = tk[k];
  }
}

// Merge PARTS sorted 16-lists per (mat,row); score = mean of 16 reciprocals.
__global__ __launch_bounds__(256) void merge_kernel(
    const float* __restrict__ cand, float* __restrict__ scores) {
  const int gid = blockIdx.x * 256 + threadIdx.x;  // 0..8191
  if (gid >= 2 * N) return;
  const int m = gid >> 12;
  const int row = gid & (N - 1);

  float tk[16];
#pragma unroll
  for (int k = 0; k < 16; ++k) tk[k] = 3.0e38f;

  for (int p = 0; p < PARTS; ++p) {
    const float* lp = cand + ((size_t)((m * PARTS + p) * N) + row) * 16;
#pragma unroll 1
    for (int k = 0; k < 16; ++k) {
      float v = lp[k];
      if (v >= tk[15]) break;  // sorted ascending: rest are larger
      topk_insert(tk, v);
    }
  }
  float s = 0.f;
#pragma unroll
  for (int k = 0; k < 16; ++k) s += 1.0f / tk[k];
  scores[(size_t)m * N + row] = s * (1.0f / 16.0f);
}

// losses = relu(neg - pos); huber(delta=1) vs 0; mean. Single block.
__global__ __launch_bounds__(256) void loss_kernel(
    const float* __restrict__ scores, float* __restrict__ out) {
  const int tid = threadIdx.x;
  float s = 0.f;
  for (int i = tid; i < N; i += 256) {
    float l = scores[N + i] - scores[i];
    l = fmaxf(l, 0.f);
    s += (l <= 1.f) ? 0.5f * l * l : (l - 0.5f);
  }
#pragma unroll
  for (int off = 32; off > 0; off >>= 1) s += __shfl_down(s, off, 64);
  __shared__ float ws[4];
  if ((tid & 63) == 0) ws[tid >> 6] = s;
  __syncthreads();
  if (tid == 0) {
    float t = ws[0] + ws[1] + ws[2] + ws[3];
    out[0] = t * (1.0f / (float)N);
  }
}

extern "C" void kernel_launch(void* const* d_in, const int* in_sizes, int n_in,
                              void* d_out, int out_size, void* d_ws, size_t ws_size,
                              hipStream_t stream) {
  const float* gt_vals = (const float*)d_in[0];       // [N, D]
  const float* train_latent = (const float*)d_in[1];  // [N, L]
  const float* test_latent = (const float*)d_in[2];   // [N, L]
  const float* W = (const float*)d_in[3];             // [L, D]
  const float* b = (const float*)d_in[4];             // [D]
  float* out = (float*)d_out;

  char* ws = (char*)d_ws;
  float* rec_test = (float*)(ws);                                  // 8 MB
  float* rec_train = (float*)(ws + (size_t)8388608);               // 8 MB
  float* cand = (float*)(ws + (size_t)16777216);                   // 8 MB (2*16*4096*16*4)
  float* scores = (float*)(ws + (size_t)16777216 + 8388608);       // 32 KB

  linear_kernel<<<dim3(N / 8, 2), 256, 0, stream>>>(
      test_latent, train_latent, W, b, rec_test, rec_train);
  dist_topk_kernel<<<dim3(N / TI, PARTS, 2), 256, 0, stream>>>(
      rec_test, gt_vals, rec_train, cand);
  merge_kernel<<<(2 * N) / 256, 256, 0, stream>>>(cand, scores);
  loss_kernel<<<1, 256, 0, stream>>>(scores, out);
}

// Round 3
// 1704.191 us; speedup vs baseline: 4.6647x; 4.6647x over previous
//
#include <hip/hip_runtime.h>
#include <math.h>

#define N 4096
#define D 512
#define L 128
#define PARTS 16
#define PARTJ (N / PARTS)   // 256
#define TI 128
#define TJ 64
#define KD 32
#define AS_STRIDE (TI + 4)  // 132
#define BS_STRIDE (TJ + 4)  // 68
#define DS_STRIDE (TJ + 4)  // 68
// shared pool: distS (TI*DS_STRIDE = 8704 floats = 34 KB) unions with
// As (KD*AS_STRIDE = 4224) + Bs (KD*BS_STRIDE = 2176) = 6400 floats,
// and with the final 128x32 merge buffer (4096 floats).
#define SMEM_FLOATS (TI * DS_STRIDE)

// Insert v into ascending sorted tk[0..15], dropping the old max.
// Caller guarantees v < tk[15].
__device__ __forceinline__ void topk_insert(float (&tk)[16], float v) {
  float x = v;
#pragma unroll
  for (int k = 0; k < 16; ++k) {
    float lo = fminf(x, tk[k]);
    float hi = fmaxf(x, tk[k]);
    tk[k] = lo;
    x = hi;
  }
}

// rec = latent @ W + b ; grid (N/8, 2), block 256. y==0 -> test, y==1 -> train
__global__ __launch_bounds__(256) void linear_kernel(
    const float* __restrict__ lat_test, const float* __restrict__ lat_train,
    const float* __restrict__ W, const float* __restrict__ bias,
    float* __restrict__ rec_test, float* __restrict__ rec_train) {
  const float* __restrict__ lat = blockIdx.y ? lat_train : lat_test;
  float* __restrict__ out = blockIdx.y ? rec_train : rec_test;
  const int r0 = blockIdx.x * 8;
  const int t = threadIdx.x;

  __shared__ float ls[8 * L];  // 8 latent rows
  {
    float4 v = *(const float4*)(lat + (size_t)r0 * L + t * 4);
    *(float4*)&ls[t * 4] = v;
  }
  __syncthreads();

  float acc[8][2];
#pragma unroll
  for (int r = 0; r < 8; ++r) { acc[r][0] = 0.f; acc[r][1] = 0.f; }

#pragma unroll 4
  for (int l = 0; l < L; ++l) {
    float w0 = W[l * D + t];
    float w1 = W[l * D + t + 256];
#pragma unroll
    for (int r = 0; r < 8; ++r) {
      float x = ls[r * L + l];
      acc[r][0] = fmaf(x, w0, acc[r][0]);
      acc[r][1] = fmaf(x, w1, acc[r][1]);
    }
  }
  float b0 = bias[t], b1 = bias[t + 256];
#pragma unroll
  for (int r = 0; r < 8; ++r) {
    out[(size_t)(r0 + r) * D + t] = acc[r][0] + b0;
    out[(size_t)(r0 + r) * D + t + 256] = acc[r][1] + b1;
  }
}

// Fused L1-cdist + per-row top-16 (smallest distances) over one j-part.
// grid (N/TI, PARTS, 2), block 256. z==0: B=gt_vals, z==1: B=rec_train.
// cand layout: [mat][part][row][16], each 16-list sorted ascending.
// NOTE: plain launch_bounds — (256,4) forced VGPR=64 and spilled 19 GB (R2).
__global__ __launch_bounds__(256) void dist_topk_kernel(
    const float* __restrict__ Arec, const float* __restrict__ Bgt,
    const float* __restrict__ Btr, float* __restrict__ cand) {
  const int itile = blockIdx.x;
  const int part = blockIdx.y;
  const int mat = blockIdx.z;
  const float* __restrict__ B = mat ? Btr : Bgt;
  const int i0 = itile * TI;
  const int jbase = part * PARTJ;

  // One pool: As/Bs live only inside the d-loop; distS only after it.
  __shared__ float smem[SMEM_FLOATS];  // 34816 B
  float* As = smem;                    // [KD][AS_STRIDE]
  float* Bs = smem + KD * AS_STRIDE;   // [KD][BS_STRIDE]
  float* distS = smem;                 // [TI][DS_STRIDE]

  const int tid = threadIdx.x;
  const int tx = tid & 15;   // j = 4*tx
  const int ty = tid >> 4;   // i = 8*ty
  // scan mapping: 2 threads per row, 32 cols each
  const int srow = tid >> 1;
  const int shalf = tid & 1;
  const int scol = shalf * 32;

  float tk[16];
#pragma unroll
  for (int k = 0; k < 16; ++k) tk[k] = 3.0e38f;

  for (int jc = 0; jc < PARTJ; jc += TJ) {
    float acc[8][4];
#pragma unroll
    for (int r = 0; r < 8; ++r)
#pragma unroll
      for (int c = 0; c < 4; ++c) acc[r][c] = 0.f;

    for (int d0 = 0; d0 < D; d0 += KD) {
      __syncthreads();  // previous consumers (compute or topk scan) done
      // stage A: TI x KD = 4096 floats, 4 float4 per thread, transposed store
#pragma unroll
      for (int s = 0; s < 4; ++s) {
        int f4 = tid + s * 256;
        int r = f4 >> 3;    // 0..127
        int c4 = f4 & 7;    // float4 within the 32-wide d-chunk
        float4 v = *(const float4*)(Arec + (size_t)(i0 + r) * D + d0 + c4 * 4);
        As[(4 * c4 + 0) * AS_STRIDE + r] = v.x;
        As[(4 * c4 + 1) * AS_STRIDE + r] = v.y;
        As[(4 * c4 + 2) * AS_STRIDE + r] = v.z;
        As[(4 * c4 + 3) * AS_STRIDE + r] = v.w;
      }
      // stage B: TJ x KD = 2048 floats, 2 float4 per thread
#pragma unroll
      for (int s = 0; s < 2; ++s) {
        int f4 = tid + s * 256;
        int r = f4 >> 3;    // 0..63
        int c4 = f4 & 7;
        float4 v = *(const float4*)(B + (size_t)(jbase + jc + r) * D + d0 + c4 * 4);
        Bs[(4 * c4 + 0) * BS_STRIDE + r] = v.x;
        Bs[(4 * c4 + 1) * BS_STRIDE + r] = v.y;
        Bs[(4 * c4 + 2) * BS_STRIDE + r] = v.z;
        Bs[(4 * c4 + 3) * BS_STRIDE + r] = v.w;
      }
      __syncthreads();

#pragma unroll
      for (int d = 0; d < KD; ++d) {
        float4 a0 = *(const float4*)&As[d * AS_STRIDE + 8 * ty];
        float4 a1 = *(const float4*)&As[d * AS_STRIDE + 8 * ty + 4];
        float4 bv4 = *(const float4*)&Bs[d * BS_STRIDE + 4 * tx];
        float av[8] = {a0.x, a0.y, a0.z, a0.w, a1.x, a1.y, a1.z, a1.w};
        float bv[4] = {bv4.x, bv4.y, bv4.z, bv4.w};
#pragma unroll
        for (int r = 0; r < 8; ++r)
#pragma unroll
          for (int c = 0; c < 4; ++c) acc[r][c] += __builtin_fabsf(av[r] - bv[c]);
      }
    }

    __syncthreads();  // all compute done reading As/Bs before distS overwrite
#pragma unroll
    for (int r = 0; r < 8; ++r)
      *(float4*)&distS[(8 * ty + r) * DS_STRIDE + 4 * tx] =
          make_float4(acc[r][0], acc[r][1], acc[r][2], acc[r][3]);
    __syncthreads();

    // all 256 threads scan: thread handles 32 cols of row srow
#pragma unroll 1
    for (int j4 = 0; j4 < 8; ++j4) {
      float4 v = *(const float4*)&distS[srow * DS_STRIDE + scol + j4 * 4];
      if (v.x < tk[15]) topk_insert(tk, v.x);
      if (v.y < tk[15]) topk_insert(tk, v.y);
      if (v.z < tk[15]) topk_insert(tk, v.z);
      if (v.w < tk[15]) topk_insert(tk, v.w);
    }
    // loop-top __syncthreads protects distS from next chunk's As/Bs staging
  }

  // Merge the two per-row half-lists (each sorted ascending) via LDS.
  __syncthreads();
  float* mergeS = smem;  // [TI][32]
#pragma unroll
  for (int k4 = 0; k4 < 4; ++k4)
    *(float4*)&mergeS[srow * 32 + shalf * 16 + k4 * 4] =
        make_float4(tk[k4 * 4], tk[k4 * 4 + 1], tk[k4 * 4 + 2], tk[k4 * 4 + 3]);
  __syncthreads();

  if (tid < TI) {
    const float* LA = &mergeS[tid * 32];
    const float* LB = LA + 16;
    const int row = i0 + tid;
    float* dst = cand + ((size_t)((mat * PARTS + part) * N) + row) * 16;
    int ia = 0, ib = 0;
#pragma unroll 1
    for (int k = 0; k < 16; ++k) {
      float a = LA[ia < 16 ? ia : 15];
      float b = LB[ib < 16 ? ib : 15];
      bool takeA = (ib >= 16) || (ia < 16 && a <= b);
      dst[k] = takeA ? a : b;
      ia += takeA ? 1 : 0;
      ib += takeA ? 0 : 1;
    }
  }
}

// Merge PARTS sorted 16-lists per (mat,row); score = mean of 16 reciprocals.
__global__ __launch_bounds__(256) void merge_kernel(
    const float* __restrict__ cand, float* __restrict__ scores) {
  const int gid = blockIdx.x * 256 + threadIdx.x;  // 0..8191
  if (gid >= 2 * N) return;
  const int m = gid >> 12;
  const int row = gid & (N - 1);

  float tk[16];
#pragma unroll
  for (int k = 0; k < 16; ++k) tk[k] = 3.0e38f;

  for (int p = 0; p < PARTS; ++p) {
    const float* lp = cand + ((size_t)((m * PARTS + p) * N) + row) * 16;
#pragma unroll 1
    for (int k = 0; k < 16; ++k) {
      float v = lp[k];
      if (v >= tk[15]) break;  // sorted ascending: rest are larger
      topk_insert(tk, v);
    }
  }
  float s = 0.f;
#pragma unroll
  for (int k = 0; k < 16; ++k) s += 1.0f / tk[k];
  scores[(size_t)m * N + row] = s * (1.0f / 16.0f);
}

// losses = relu(neg - pos); huber(delta=1) vs 0; mean. Single block.
__global__ __launch_bounds__(256) void loss_kernel(
    const float* __restrict__ scores, float* __restrict__ out) {
  const int tid = threadIdx.x;
  float s = 0.f;
  for (int i = tid; i < N; i += 256) {
    float l = scores[N + i] - scores[i];
    l = fmaxf(l, 0.f);
    s += (l <= 1.f) ? 0.5f * l * l : (l - 0.5f);
  }
#pragma unroll
  for (int off = 32; off > 0; off >>= 1) s += __shfl_down(s, off, 64);
  __shared__ float ws[4];
  if ((tid & 63) == 0) ws[tid >> 6] = s;
  __syncthreads();
  if (tid == 0) {
    float t = ws[0] + ws[1] + ws[2] + ws[3];
    out[0] = t * (1.0f / (float)N);
  }
}

extern "C" void kernel_launch(void* const* d_in, const int* in_sizes, int n_in,
                              void* d_out, int out_size, void* d_ws, size_t ws_size,
                              hipStream_t stream) {
  const float* gt_vals = (const float*)d_in[0];       // [N, D]
  const float* train_latent = (const float*)d_in[1];  // [N, L]
  const float* test_latent = (const float*)d_in[2];   // [N, L]
  const float* W = (const float*)d_in[3];             // [L, D]
  const float* b = (const float*)d_in[4];             // [D]
  float* out = (float*)d_out;

  char* ws = (char*)d_ws;
  float* rec_test = (float*)(ws);                                  // 8 MB
  float* rec_train = (float*)(ws + (size_t)8388608);               // 8 MB
  float* cand = (float*)(ws + (size_t)16777216);                   // 8 MB (2*16*4096*16*4)
  float* scores = (float*)(ws + (size_t)16777216 + 8388608);       // 32 KB

  linear_kernel<<<dim3(N / 8, 2), 256, 0, stream>>>(
      test_latent, train_latent, W, b, rec_test, rec_train);
  dist_topk_kernel<<<dim3(N / TI, PARTS, 2), 256, 0, stream>>>(
      rec_test, gt_vals, rec_train, cand);
  merge_kernel<<<(2 * N) / 256, 256, 0, stream>>>(cand, scores);
  loss_kernel<<<1, 256, 0, stream>>>(scores, out);
}

// Round 4
// 1090.540 us; speedup vs baseline: 7.2896x; 1.5627x over previous
//
#include <hip/hip_runtime.h>
#include <math.h>

#define N 4096
#define D 512
#define L 128

// ---------------- fast path (needs ~144 MB ws) ----------------
#define DTI 128
#define DTJ 128
#define DKD 16
#define DAS 132   // A LDS stride
#define DBS 144   // B LDS stride; col swizzle j + 4*(j>>5) keeps 16B align,
                  // makes the 8*tx read pattern a free 2-way (was 4-way)

// ---------------- fallback path (R3, ~25 MB ws) ----------------
#define PARTS 16
#define PARTJ (N / PARTS)
#define TI 128
#define TJ 64
#define KD 32
#define AS_STRIDE (TI + 4)
#define BS_STRIDE (TJ + 4)
#define DS_STRIDE (TJ + 4)
#define SMEM_FLOATS (TI * DS_STRIDE)

// Insert v into ascending sorted tk[0..15], dropping the old max.
__device__ __forceinline__ void topk_insert(float (&tk)[16], float v) {
  float x = v;
#pragma unroll
  for (int k = 0; k < 16; ++k) {
    float lo = fminf(x, tk[k]);
    float hi = fmaxf(x, tk[k]);
    tk[k] = lo;
    x = hi;
  }
}

// rec = latent @ W + b ; grid (N/8, 2), block 256.
__global__ __launch_bounds__(256) void linear_kernel(
    const float* __restrict__ lat_test, const float* __restrict__ lat_train,
    const float* __restrict__ W, const float* __restrict__ bias,
    float* __restrict__ rec_test, float* __restrict__ rec_train) {
  const float* __restrict__ lat = blockIdx.y ? lat_train : lat_test;
  float* __restrict__ out = blockIdx.y ? rec_train : rec_test;
  const int r0 = blockIdx.x * 8;
  const int t = threadIdx.x;

  __shared__ float ls[8 * L];
  {
    float4 v = *(const float4*)(lat + (size_t)r0 * L + t * 4);
    *(float4*)&ls[t * 4] = v;
  }
  __syncthreads();

  float acc[8][2];
#pragma unroll
  for (int r = 0; r < 8; ++r) { acc[r][0] = 0.f; acc[r][1] = 0.f; }

#pragma unroll 4
  for (int l = 0; l < L; ++l) {
    float w0 = W[l * D + t];
    float w1 = W[l * D + t + 256];
#pragma unroll
    for (int r = 0; r < 8; ++r) {
      float x = ls[r * L + l];
      acc[r][0] = fmaf(x, w0, acc[r][0]);
      acc[r][1] = fmaf(x, w1, acc[r][1]);
    }
  }
  float b0 = bias[t], b1 = bias[t + 256];
#pragma unroll
  for (int r = 0; r < 8; ++r) {
    out[(size_t)(r0 + r) * D + t] = acc[r][0] + b0;
    out[(size_t)(r0 + r) * D + t + 256] = acc[r][1] + b1;
  }
}

// ============ FAST PATH ============
// L1 cdist, 128x128 tile, 8x8 per thread, writes raw distances to global.
// grid (N/128, N/128, 2); z==0: B=gt_vals (pos), z==1: B=rec_train (neg).
// amdgpu_waves_per_eu(4,4): pin VGPR<=128 for 4 waves/SIMD; both ends pinned
// so the allocator doesn't chase 8 waves like __launch_bounds__(256,4) did (R2).
__global__ __launch_bounds__(256) __attribute__((amdgpu_waves_per_eu(4, 4)))
void dist_kernel(const float* __restrict__ Arec, const float* __restrict__ Bgt,
                 const float* __restrict__ Btr, float* __restrict__ dist) {
  const int i0 = blockIdx.x * DTI;
  const int j0 = blockIdx.y * DTJ;
  const int mat = blockIdx.z;
  const float* __restrict__ B = mat ? Btr : Bgt;
  float* __restrict__ out = dist + (size_t)mat * N * N;

  __shared__ float As[DKD * DAS];  // [d][i], 8448 B
  __shared__ float Bs[DKD * DBS];  // [d][j swizzled], 9216 B

  const int tid = threadIdx.x;
  const int tx = tid & 15;
  const int ty = tid >> 4;
  const int aoff = 8 * ty;
  const int boff = 8 * tx + 4 * (tx >> 2);  // swizzled column base

  // staging maps: 512 float4 per tile, 2 per thread
  const int idx0 = tid, idx1 = tid + 256;
  const int rA0 = idx0 >> 2, cA0 = idx0 & 3;
  const int rA1 = idx1 >> 2, cA1 = idx1 & 3;
  const float* apA0 = Arec + (size_t)(i0 + rA0) * D + cA0 * 4;
  const float* apA1 = Arec + (size_t)(i0 + rA1) * D + cA1 * 4;
  const float* bp0 = B + (size_t)(j0 + rA0) * D + cA0 * 4;
  const float* bp1 = B + (size_t)(j0 + rA1) * D + cA1 * 4;
  float* wa0 = &As[(4 * cA0) * DAS + rA0];
  float* wa1 = &As[(4 * cA1) * DAS + rA1];
  const int jc0 = rA0 + 4 * (rA0 >> 5);
  const int jc1 = rA1 + 4 * (rA1 >> 5);
  float* wb0 = &Bs[(4 * cA0) * DBS + jc0];
  float* wb1 = &Bs[(4 * cA1) * DBS + jc1];

  float acc[8][8];
#pragma unroll
  for (int r = 0; r < 8; ++r)
#pragma unroll
    for (int c = 0; c < 8; ++c) acc[r][c] = 0.f;

  for (int d0 = 0; d0 < D; d0 += DKD) {
    __syncthreads();
    {
      float4 va0 = *(const float4*)(apA0 + d0);
      float4 va1 = *(const float4*)(apA1 + d0);
      float4 vb0 = *(const float4*)(bp0 + d0);
      float4 vb1 = *(const float4*)(bp1 + d0);
      wa0[0 * DAS] = va0.x; wa0[1 * DAS] = va0.y; wa0[2 * DAS] = va0.z; wa0[3 * DAS] = va0.w;
      wa1[0 * DAS] = va1.x; wa1[1 * DAS] = va1.y; wa1[2 * DAS] = va1.z; wa1[3 * DAS] = va1.w;
      wb0[0 * DBS] = vb0.x; wb0[1 * DBS] = vb0.y; wb0[2 * DBS] = vb0.z; wb0[3 * DBS] = vb0.w;
      wb1[0 * DBS] = vb1.x; wb1[1 * DBS] = vb1.y; wb1[2 * DBS] = vb1.z; wb1[3 * DBS] = vb1.w;
    }
    __syncthreads();

#pragma unroll 2
    for (int d = 0; d < DKD; ++d) {
      float4 a0 = *(const float4*)&As[d * DAS + aoff];
      float4 a1 = *(const float4*)&As[d * DAS + aoff + 4];
      float4 b0 = *(const float4*)&Bs[d * DBS + boff];
      float4 b1 = *(const float4*)&Bs[d * DBS + boff + 4];
      float av[8] = {a0.x, a0.y, a0.z, a0.w, a1.x, a1.y, a1.z, a1.w};
      float bv[8] = {b0.x, b0.y, b0.z, b0.w, b1.x, b1.y, b1.z, b1.w};
#pragma unroll
      for (int r = 0; r < 8; ++r)
#pragma unroll
        for (int c = 0; c < 8; ++c) acc[r][c] += fabsf(av[r] - bv[c]);
    }
  }

#pragma unroll
  for (int r = 0; r < 8; ++r) {
    float* dst = out + (size_t)(i0 + 8 * ty + r) * N + j0 + 8 * tx;
    *(float4*)dst = make_float4(acc[r][0], acc[r][1], acc[r][2], acc[r][3]);
    *(float4*)(dst + 4) = make_float4(acc[r][4], acc[r][5], acc[r][6], acc[r][7]);
  }
}

// One block per (mat,row): top-16 smallest of 4096 + score. grid 2*N.
__global__ __launch_bounds__(256) void row_topk_kernel(
    const float* __restrict__ dist, float* __restrict__ scores) {
  const float* __restrict__ p = dist + (size_t)blockIdx.x * N;
  const int tid = threadIdx.x;

  float tk[16];
#pragma unroll
  for (int k = 0; k < 16; ++k) tk[k] = 3.0e38f;

#pragma unroll
  for (int q = 0; q < 4; ++q) {
    float4 v = *(const float4*)(p + tid * 16 + q * 4);
    if (v.x < tk[15]) topk_insert(tk, v.x);
    if (v.y < tk[15]) topk_insert(tk, v.y);
    if (v.z < tk[15]) topk_insert(tk, v.z);
    if (v.w < tk[15]) topk_insert(tk, v.w);
  }

  __shared__ float lists[256 * 16];  // 16 KB
#pragma unroll
  for (int k = 0; k < 16; ++k) lists[tid * 16 + k] = tk[k];

  for (int stride = 1; stride < 256; stride <<= 1) {
    __syncthreads();
    if ((tid & (2 * stride - 1)) == 0) {
      const float* LA = &lists[tid * 16];
      const float* LB = &lists[(tid + stride) * 16];
      float outv[16];
      int ia = 0, ib = 0;
#pragma unroll
      for (int k = 0; k < 16; ++k) {
        float a = LA[ia < 16 ? ia : 15];
        float b = LB[ib < 16 ? ib : 15];
        bool takeA = (ib >= 16) || (ia < 16 && a <= b);
        outv[k] = takeA ? a : b;
        ia += takeA ? 1 : 0;
        ib += takeA ? 0 : 1;
      }
#pragma unroll
      for (int k = 0; k < 16; ++k) lists[tid * 16 + k] = outv[k];
    }
  }
  __syncthreads();
  if (tid == 0) {
    float s = 0.f;
#pragma unroll
    for (int k = 0; k < 16; ++k) s += 1.0f / lists[k];
    scores[blockIdx.x] = s * (1.0f / 16.0f);
  }
}

// ============ FALLBACK PATH (R3, proven) ============
__global__ __launch_bounds__(256) void dist_topk_kernel(
    const float* __restrict__ Arec, const float* __restrict__ Bgt,
    const float* __restrict__ Btr, float* __restrict__ cand) {
  const int itile = blockIdx.x;
  const int part = blockIdx.y;
  const int mat = blockIdx.z;
  const float* __restrict__ B = mat ? Btr : Bgt;
  const int i0 = itile * TI;
  const int jbase = part * PARTJ;

  __shared__ float smem[SMEM_FLOATS];
  float* As = smem;
  float* Bs = smem + KD * AS_STRIDE;
  float* distS = smem;

  const int tid = threadIdx.x;
  const int tx = tid & 15;
  const int ty = tid >> 4;
  const int srow = tid >> 1;
  const int shalf = tid & 1;
  const int scol = shalf * 32;

  float tk[16];
#pragma unroll
  for (int k = 0; k < 16; ++k) tk[k] = 3.0e38f;

  for (int jc = 0; jc < PARTJ; jc += TJ) {
    float acc[8][4];
#pragma unroll
    for (int r = 0; r < 8; ++r)
#pragma unroll
      for (int c = 0; c < 4; ++c) acc[r][c] = 0.f;

    for (int d0 = 0; d0 < D; d0 += KD) {
      __syncthreads();
#pragma unroll
      for (int s = 0; s < 4; ++s) {
        int f4 = tid + s * 256;
        int r = f4 >> 3;
        int c4 = f4 & 7;
        float4 v = *(const float4*)(Arec + (size_t)(i0 + r) * D + d0 + c4 * 4);
        As[(4 * c4 + 0) * AS_STRIDE + r] = v.x;
        As[(4 * c4 + 1) * AS_STRIDE + r] = v.y;
        As[(4 * c4 + 2) * AS_STRIDE + r] = v.z;
        As[(4 * c4 + 3) * AS_STRIDE + r] = v.w;
      }
#pragma unroll
      for (int s = 0; s < 2; ++s) {
        int f4 = tid + s * 256;
        int r = f4 >> 3;
        int c4 = f4 & 7;
        float4 v = *(const float4*)(B + (size_t)(jbase + jc + r) * D + d0 + c4 * 4);
        Bs[(4 * c4 + 0) * BS_STRIDE + r] = v.x;
        Bs[(4 * c4 + 1) * BS_STRIDE + r] = v.y;
        Bs[(4 * c4 + 2) * BS_STRIDE + r] = v.z;
        Bs[(4 * c4 + 3) * BS_STRIDE + r] = v.w;
      }
      __syncthreads();

#pragma unroll
      for (int d = 0; d < KD; ++d) {
        float4 a0 = *(const float4*)&As[d * AS_STRIDE + 8 * ty];
        float4 a1 = *(const float4*)&As[d * AS_STRIDE + 8 * ty + 4];
        float4 bv4 = *(const float4*)&Bs[d * BS_STRIDE + 4 * tx];
        float av[8] = {a0.x, a0.y, a0.z, a0.w, a1.x, a1.y, a1.z, a1.w};
        float bv[4] = {bv4.x, bv4.y, bv4.z, bv4.w};
#pragma unroll
        for (int r = 0; r < 8; ++r)
#pragma unroll
          for (int c = 0; c < 4; ++c) acc[r][c] += __builtin_fabsf(av[r] - bv[c]);
      }
    }

    __syncthreads();
#pragma unroll
    for (int r = 0; r < 8; ++r)
      *(float4*)&distS[(8 * ty + r) * DS_STRIDE + 4 * tx] =
          make_float4(acc[r][0], acc[r][1], acc[r][2], acc[r][3]);
    __syncthreads();

#pragma unroll 1
    for (int j4 = 0; j4 < 8; ++j4) {
      float4 v = *(const float4*)&distS[srow * DS_STRIDE + scol + j4 * 4];
      if (v.x < tk[15]) topk_insert(tk, v.x);
      if (v.y < tk[15]) topk_insert(tk, v.y);
      if (v.z < tk[15]) topk_insert(tk, v.z);
      if (v.w < tk[15]) topk_insert(tk, v.w);
    }
  }

  __syncthreads();
  float* mergeS = smem;
#pragma unroll
  for (int k4 = 0; k4 < 4; ++k4)
    *(float4*)&mergeS[srow * 32 + shalf * 16 + k4 * 4] =
        make_float4(tk[k4 * 4], tk[k4 * 4 + 1], tk[k4 * 4 + 2], tk[k4 * 4 + 3]);
  __syncthreads();

  if (tid < TI) {
    const float* LA = &mergeS[tid * 32];
    const float* LB = LA + 16;
    const int row = i0 + tid;
    float* dst = cand + ((size_t)((mat * PARTS + part) * N) + row) * 16;
    int ia = 0, ib = 0;
#pragma unroll 1
    for (int k = 0; k < 16; ++k) {
      float a = LA[ia < 16 ? ia : 15];
      float b = LB[ib < 16 ? ib : 15];
      bool takeA = (ib >= 16) || (ia < 16 && a <= b);
      dst[k] = takeA ? a : b;
      ia += takeA ? 1 : 0;
      ib += takeA ? 0 : 1;
    }
  }
}

__global__ __launch_bounds__(256) void merge_kernel(
    const float* __restrict__ cand, float* __restrict__ scores) {
  const int gid = blockIdx.x * 256 + threadIdx.x;
  if (gid >= 2 * N) return;
  const int m = gid >> 12;
  const int row = gid & (N - 1);

  float tk[16];
#pragma unroll
  for (int k = 0; k < 16; ++k) tk[k] = 3.0e38f;

  for (int p = 0; p < PARTS; ++p) {
    const float* lp = cand + ((size_t)((m * PARTS + p) * N) + row) * 16;
#pragma unroll 1
    for (int k = 0; k < 16; ++k) {
      float v = lp[k];
      if (v >= tk[15]) break;
      topk_insert(tk, v);
    }
  }
  float s = 0.f;
#pragma unroll
  for (int k = 0; k < 16; ++k) s += 1.0f / tk[k];
  scores[(size_t)m * N + row] = s * (1.0f / 16.0f);
}

// losses = relu(neg - pos); huber(delta=1) vs 0; mean. Single block.
__global__ __launch_bounds__(256) void loss_kernel(
    const float* __restrict__ scores, float* __restrict__ out) {
  const int tid = threadIdx.x;
  float s = 0.f;
  for (int i = tid; i < N; i += 256) {
    float l = scores[N + i] - scores[i];
    l = fmaxf(l, 0.f);
    s += (l <= 1.f) ? 0.5f * l * l : (l - 0.5f);
  }
#pragma unroll
  for (int off = 32; off > 0; off >>= 1) s += __shfl_down(s, off, 64);
  __shared__ float ws[4];
  if ((tid & 63) == 0) ws[tid >> 6] = s;
  __syncthreads();
  if (tid == 0) {
    float t = ws[0] + ws[1] + ws[2] + ws[3];
    out[0] = t * (1.0f / (float)N);
  }
}

extern "C" void kernel_launch(void* const* d_in, const int* in_sizes, int n_in,
                              void* d_out, int out_size, void* d_ws, size_t ws_size,
                              hipStream_t stream) {
  const float* gt_vals = (const float*)d_in[0];
  const float* train_latent = (const float*)d_in[1];
  const float* test_latent = (const float*)d_in[2];
  const float* W = (const float*)d_in[3];
  const float* b = (const float*)d_in[4];
  float* out = (float*)d_out;

  char* ws = (char*)d_ws;
  const size_t REC = 8388608;          // 8 MB each
  const size_t DIST = 134217728;       // 128 MB
  const size_t NEED_FAST = 2 * REC + DIST + 32768;

  float* rec_test = (float*)(ws);
  float* rec_train = (float*)(ws + REC);

  linear_kernel<<<dim3(N / 8, 2), 256, 0, stream>>>(
      test_latent, train_latent, W, b, rec_test, rec_train);

  if (ws_size >= NEED_FAST) {
    float* dist = (float*)(ws + 2 * REC);
    float* scores = (float*)(ws + 2 * REC + DIST);
    dist_kernel<<<dim3(N / DTI, N / DTJ, 2), 256, 0, stream>>>(
        rec_test, gt_vals, rec_train, dist);
    row_topk_kernel<<<2 * N, 256, 0, stream>>>(dist, scores);
    loss_kernel<<<1, 256, 0, stream>>>(scores, out);
  } else {
    float* cand = (float*)(ws + 2 * REC);                 // 8 MB
    float* scores = (float*)(ws + 2 * REC + 8388608);     // 32 KB
    dist_topk_kernel<<<dim3(N / TI, PARTS, 2), 256, 0, stream>>>(
        rec_test, gt_vals, rec_train, cand);
    merge_kernel<<<(2 * N) / 256, 256, 0, stream>>>(cand, scores);
    loss_kernel<<<1, 256, 0, stream>>>(scores, out);
  }
}

// Round 6
// 789.566 us; speedup vs baseline: 10.0683x; 1.3812x over previous
//
#include <hip/hip_runtime.h>
#include <math.h>

#define N 4096
#define D 512
#define L 128

// ---------------- fast path (needs ~144 MB ws) ----------------
#define DTI 128
#define DTJ 128
#define DKD 32
#define DAS 132   // A LDS stride
#define DBS 144   // B LDS stride; col swizzle j + 4*(j>>5) keeps 16B align,
                  // makes the 8*tx read pattern a free 2-way (was 4-way)

// ---------------- fallback path (R3, ~25 MB ws) ----------------
#define PARTS 16
#define PARTJ (N / PARTS)
#define TI 128
#define TJ 64
#define KD 32
#define AS_STRIDE (TI + 4)
#define BS_STRIDE (TJ + 4)
#define DS_STRIDE (TJ + 4)
#define SMEM_FLOATS (TI * DS_STRIDE)

// acc += |t| in exactly one VOP3 instr (abs input modifier).
// fabsf() in C left us at ~4.7 VALU slots/element (R4 post-mortem).
#define ACC_ABS(accv, t) \
  asm("v_add_f32 %0, %0, abs(%1)" : "+v"(accv) : "v"(t))

// Insert v into ascending sorted tk[0..15], dropping the old max.
__device__ __forceinline__ void topk_insert(float (&tk)[16], float v) {
  float x = v;
#pragma unroll
  for (int k = 0; k < 16; ++k) {
    float lo = fminf(x, tk[k]);
    float hi = fmaxf(x, tk[k]);
    tk[k] = lo;
    x = hi;
  }
}

// rec = latent @ W + b ; grid (N/8, 2), block 256.
__global__ __launch_bounds__(256) void linear_kernel(
    const float* __restrict__ lat_test, const float* __restrict__ lat_train,
    const float* __restrict__ W, const float* __restrict__ bias,
    float* __restrict__ rec_test, float* __restrict__ rec_train) {
  const float* __restrict__ lat = blockIdx.y ? lat_train : lat_test;
  float* __restrict__ out = blockIdx.y ? rec_train : rec_test;
  const int r0 = blockIdx.x * 8;
  const int t = threadIdx.x;

  __shared__ float ls[8 * L];
  {
    float4 v = *(const float4*)(lat + (size_t)r0 * L + t * 4);
    *(float4*)&ls[t * 4] = v;
  }
  __syncthreads();

  float acc[8][2];
#pragma unroll
  for (int r = 0; r < 8; ++r) { acc[r][0] = 0.f; acc[r][1] = 0.f; }

#pragma unroll 4
  for (int l = 0; l < L; ++l) {
    float w0 = W[l * D + t];
    float w1 = W[l * D + t + 256];
#pragma unroll
    for (int r = 0; r < 8; ++r) {
      float x = ls[r * L + l];
      acc[r][0] = fmaf(x, w0, acc[r][0]);
      acc[r][1] = fmaf(x, w1, acc[r][1]);
    }
  }
  float b0 = bias[t], b1 = bias[t + 256];
#pragma unroll
  for (int r = 0; r < 8; ++r) {
    out[(size_t)(r0 + r) * D + t] = acc[r][0] + b0;
    out[(size_t)(r0 + r) * D + t + 256] = acc[r][1] + b1;
  }
}

// ============ FAST PATH ============
// L1 cdist, 128x128 tile, 8x8 per thread, raw distances to global.
// grid (N/128, N/128, 2); z==0: B=gt_vals (pos), z==1: B=rec_train (neg).
// waves_per_eu(4,4): pin both ends (R2: __launch_bounds__(256,4) chased
// 8 waves -> 64 VGPR -> 19 GB spill).
__global__ __launch_bounds__(256) __attribute__((amdgpu_waves_per_eu(4, 4)))
void dist_kernel(const float* __restrict__ Arec, const float* __restrict__ Bgt,
                 const float* __restrict__ Btr, float* __restrict__ dist) {
  const int i0 = blockIdx.x * DTI;
  const int j0 = blockIdx.y * DTJ;
  const int mat = blockIdx.z;
  const float* __restrict__ B = mat ? Btr : Bgt;
  float* __restrict__ out = dist + (size_t)mat * N * N;

  __shared__ float As[DKD * DAS];  // [d][i], 16896 B
  __shared__ float Bs[DKD * DBS];  // [d][j swizzled], 18432 B

  const int tid = threadIdx.x;
  const int tx = tid & 15;
  const int ty = tid >> 4;
  const int aoff = 8 * ty;
  const int boff = 8 * tx + 4 * (tx >> 2);  // swizzled column base

  // staging: tile is 128 rows x 32 d = 1024 float4, 4 per thread.
  // idx = tid + s*256: r = idx>>3 (0..127), c4 = idx&7 (d-offset 4*c4)
  float acc[8][8];
#pragma unroll
  for (int r = 0; r < 8; ++r)
#pragma unroll
    for (int c = 0; c < 8; ++c) acc[r][c] = 0.f;

  for (int d0 = 0; d0 < D; d0 += DKD) {
    __syncthreads();
#pragma unroll
    for (int s = 0; s < 4; ++s) {
      const int idx = tid + s * 256;
      const int r = idx >> 3;
      const int c4 = idx & 7;
      float4 va = *(const float4*)(Arec + (size_t)(i0 + r) * D + d0 + c4 * 4);
      float4 vb = *(const float4*)(B + (size_t)(j0 + r) * D + d0 + c4 * 4);
      As[(4 * c4 + 0) * DAS + r] = va.x;
      As[(4 * c4 + 1) * DAS + r] = va.y;
      As[(4 * c4 + 2) * DAS + r] = va.z;
      As[(4 * c4 + 3) * DAS + r] = va.w;
      const int jc = r + 4 * (r >> 5);
      Bs[(4 * c4 + 0) * DBS + jc] = vb.x;
      Bs[(4 * c4 + 1) * DBS + jc] = vb.y;
      Bs[(4 * c4 + 2) * DBS + jc] = vb.z;
      Bs[(4 * c4 + 3) * DBS + jc] = vb.w;
    }
    __syncthreads();

#pragma unroll 4
    for (int d = 0; d < DKD; ++d) {
      float4 a0 = *(const float4*)&As[d * DAS + aoff];
      float4 a1 = *(const float4*)&As[d * DAS + aoff + 4];
      float4 b0 = *(const float4*)&Bs[d * DBS + boff];
      float4 b1 = *(const float4*)&Bs[d * DBS + boff + 4];
#define ROWC(r, av)                                       \
  {                                                       \
    float t0 = av - b0.x; ACC_ABS(acc[r][0], t0);         \
    float t1 = av - b0.y; ACC_ABS(acc[r][1], t1);         \
    float t2 = av - b0.z; ACC_ABS(acc[r][2], t2);         \
    float t3 = av - b0.w; ACC_ABS(acc[r][3], t3);         \
    float t4 = av - b1.x; ACC_ABS(acc[r][4], t4);         \
    float t5 = av - b1.y; ACC_ABS(acc[r][5], t5);         \
    float t6 = av - b1.z; ACC_ABS(acc[r][6], t6);         \
    float t7 = av - b1.w; ACC_ABS(acc[r][7], t7);         \
  }
      ROWC(0, a0.x) ROWC(1, a0.y) ROWC(2, a0.z) ROWC(3, a0.w)
      ROWC(4, a1.x) ROWC(5, a1.y) ROWC(6, a1.z) ROWC(7, a1.w)
#undef ROWC
    }
  }

#pragma unroll
  for (int r = 0; r < 8; ++r) {
    float* dst = out + (size_t)(i0 + 8 * ty + r) * N + j0 + 8 * tx;
    *(float4*)dst = make_float4(acc[r][0], acc[r][1], acc[r][2], acc[r][3]);
    *(float4*)(dst + 4) = make_float4(acc[r][4], acc[r][5], acc[r][6], acc[r][7]);
  }
}

// One block per (mat,row): top-16 smallest of 4096 + score. grid 2*N.
__global__ __launch_bounds__(256) void row_topk_kernel(
    const float* __restrict__ dist, float* __restrict__ scores) {
  const float* __restrict__ p = dist + (size_t)blockIdx.x * N;
  const int tid = threadIdx.x;

  float tk[16];
#pragma unroll
  for (int k = 0; k < 16; ++k) tk[k] = 3.0e38f;

#pragma unroll
  for (int q = 0; q < 4; ++q) {
    float4 v = *(const float4*)(p + tid * 16 + q * 4);
    if (v.x < tk[15]) topk_insert(tk, v.x);
    if (v.y < tk[15]) topk_insert(tk, v.y);
    if (v.z < tk[15]) topk_insert(tk, v.z);
    if (v.w < tk[15]) topk_insert(tk, v.w);
  }

  __shared__ float lists[256 * 16];  // 16 KB
#pragma unroll
  for (int k = 0; k < 16; ++k) lists[tid * 16 + k] = tk[k];

  for (int stride = 1; stride < 256; stride <<= 1) {
    __syncthreads();
    if ((tid & (2 * stride - 1)) == 0) {
      const float* LA = &lists[tid * 16];
      const float* LB = &lists[(tid + stride) * 16];
      float outv[16];
      int ia = 0, ib = 0;
#pragma unroll
      for (int k = 0; k < 16; ++k) {
        float a = LA[ia < 16 ? ia : 15];
        float b = LB[ib < 16 ? ib : 15];
        bool takeA = (ib >= 16) || (ia < 16 && a <= b);
        outv[k] = takeA ? a : b;
        ia += takeA ? 1 : 0;
        ib += takeA ? 0 : 1;
      }
#pragma unroll
      for (int k = 0; k < 16; ++k) lists[tid * 16 + k] = outv[k];
    }
  }
  __syncthreads();
  if (tid == 0) {
    float s = 0.f;
#pragma unroll
    for (int k = 0; k < 16; ++k) s += 1.0f / lists[k];
    scores[blockIdx.x] = s * (1.0f / 16.0f);
  }
}

// ============ FALLBACK PATH (R3, proven) ============
__global__ __launch_bounds__(256) void dist_topk_kernel(
    const float* __restrict__ Arec, const float* __restrict__ Bgt,
    const float* __restrict__ Btr, float* __restrict__ cand) {
  const int itile = blockIdx.x;
  const int part = blockIdx.y;
  const int mat = blockIdx.z;
  const float* __restrict__ B = mat ? Btr : Bgt;
  const int i0 = itile * TI;
  const int jbase = part * PARTJ;

  __shared__ float smem[SMEM_FLOATS];
  float* As = smem;
  float* Bs = smem + KD * AS_STRIDE;
  float* distS = smem;

  const int tid = threadIdx.x;
  const int tx = tid & 15;
  const int ty = tid >> 4;
  const int srow = tid >> 1;
  const int shalf = tid & 1;
  const int scol = shalf * 32;

  float tk[16];
#pragma unroll
  for (int k = 0; k < 16; ++k) tk[k] = 3.0e38f;

  for (int jc = 0; jc < PARTJ; jc += TJ) {
    float acc[8][4];
#pragma unroll
    for (int r = 0; r < 8; ++r)
#pragma unroll
      for (int c = 0; c < 4; ++c) acc[r][c] = 0.f;

    for (int d0 = 0; d0 < D; d0 += KD) {
      __syncthreads();
#pragma unroll
      for (int s = 0; s < 4; ++s) {
        int f4 = tid + s * 256;
        int r = f4 >> 3;
        int c4 = f4 & 7;
        float4 v = *(const float4*)(Arec + (size_t)(i0 + r) * D + d0 + c4 * 4);
        As[(4 * c4 + 0) * AS_STRIDE + r] = v.x;
        As[(4 * c4 + 1) * AS_STRIDE + r] = v.y;
        As[(4 * c4 + 2) * AS_STRIDE + r] = v.z;
        As[(4 * c4 + 3) * AS_STRIDE + r] = v.w;
      }
#pragma unroll
      for (int s = 0; s < 2; ++s) {
        int f4 = tid + s * 256;
        int r = f4 >> 3;
        int c4 = f4 & 7;
        float4 v = *(const float4*)(B + (size_t)(jbase + jc + r) * D + d0 + c4 * 4);
        Bs[(4 * c4 + 0) * BS_STRIDE + r] = v.x;
        Bs[(4 * c4 + 1) * BS_STRIDE + r] = v.y;
        Bs[(4 * c4 + 2) * BS_STRIDE + r] = v.z;
        Bs[(4 * c4 + 3) * BS_STRIDE + r] = v.w;
      }
      __syncthreads();

#pragma unroll
      for (int d = 0; d < KD; ++d) {
        float4 a0 = *(const float4*)&As[d * AS_STRIDE + 8 * ty];
        float4 a1 = *(const float4*)&As[d * AS_STRIDE + 8 * ty + 4];
        float4 bv4 = *(const float4*)&Bs[d * BS_STRIDE + 4 * tx];
        float av[8] = {a0.x, a0.y, a0.z, a0.w, a1.x, a1.y, a1.z, a1.w};
        float bv[4] = {bv4.x, bv4.y, bv4.z, bv4.w};
#pragma unroll
        for (int r = 0; r < 8; ++r)
#pragma unroll
          for (int c = 0; c < 4; ++c) acc[r][c] += __builtin_fabsf(av[r] - bv[c]);
      }
    }

    __syncthreads();
#pragma unroll
    for (int r = 0; r < 8; ++r)
      *(float4*)&distS[(8 * ty + r) * DS_STRIDE + 4 * tx] =
          make_float4(acc[r][0], acc[r][1], acc[r][2], acc[r][3]);
    __syncthreads();

#pragma unroll 1
    for (int j4 = 0; j4 < 8; ++j4) {
      float4 v = *(const float4*)&distS[srow * DS_STRIDE + scol + j4 * 4];
      if (v.x < tk[15]) topk_insert(tk, v.x);
      if (v.y < tk[15]) topk_insert(tk, v.y);
      if (v.z < tk[15]) topk_insert(tk, v.z);
      if (v.w < tk[15]) topk_insert(tk, v.w);
    }
  }

  __syncthreads();
  float* mergeS = smem;
#pragma unroll
  for (int k4 = 0; k4 < 4; ++k4)
    *(float4*)&mergeS[srow * 32 + shalf * 16 + k4 * 4] =
        make_float4(tk[k4 * 4], tk[k4 * 4 + 1], tk[k4 * 4 + 2], tk[k4 * 4 + 3]);
  __syncthreads();

  if (tid < TI) {
    const float* LA = &mergeS[tid * 32];
    const float* LB = LA + 16;
    const int row = i0 + tid;
    float* dst = cand + ((size_t)((mat * PARTS + part) * N) + row) * 16;
    int ia = 0, ib = 0;
#pragma unroll 1
    for (int k = 0; k < 16; ++k) {
      float a = LA[ia < 16 ? ia : 15];
      float b = LB[ib < 16 ? ib : 15];
      bool takeA = (ib >= 16) || (ia < 16 && a <= b);
      dst[k] = takeA ? a : b;
      ia += takeA ? 1 : 0;
      ib += takeA ? 0 : 1;
    }
  }
}

__global__ __launch_bounds__(256) void merge_kernel(
    const float* __restrict__ cand, float* __restrict__ scores) {
  const int gid = blockIdx.x * 256 + threadIdx.x;
  if (gid >= 2 * N) return;
  const int m = gid >> 12;
  const int row = gid & (N - 1);

  float tk[16];
#pragma unroll
  for (int k = 0; k < 16; ++k) tk[k] = 3.0e38f;

  for (int p = 0; p < PARTS; ++p) {
    const float* lp = cand + ((size_t)((m * PARTS + p) * N) + row) * 16;
#pragma unroll 1
    for (int k = 0; k < 16; ++k) {
      float v = lp[k];
      if (v >= tk[15]) break;
      topk_insert(tk, v);
    }
  }
  float s = 0.f;
#pragma unroll
  for (int k = 0; k < 16; ++k) s += 1.0f / tk[k];
  scores[(size_t)m * N + row] = s * (1.0f / 16.0f);
}

// losses = relu(neg - pos); huber(delta=1) vs 0; mean. Single block.
__global__ __launch_bounds__(256) void loss_kernel(
    const float* __restrict__ scores, float* __restrict__ out) {
  const int tid = threadIdx.x;
  float s = 0.f;
  for (int i = tid; i < N; i += 256) {
    float l = scores[N + i] - scores[i];
    l = fmaxf(l, 0.f);
    s += (l <= 1.f) ? 0.5f * l * l : (l - 0.5f);
  }
#pragma unroll
  for (int off = 32; off > 0; off >>= 1) s += __shfl_down(s, off, 64);
  __shared__ float ws[4];
  if ((tid & 63) == 0) ws[tid >> 6] = s;
  __syncthreads();
  if (tid == 0) {
    float t = ws[0] + ws[1] + ws[2] + ws[3];
    out[0] = t * (1.0f / (float)N);
  }
}

extern "C" void kernel_launch(void* const* d_in, const int* in_sizes, int n_in,
                              void* d_out, int out_size, void* d_ws, size_t ws_size,
                              hipStream_t stream) {
  const float* gt_vals = (const float*)d_in[0];
  const float* train_latent = (const float*)d_in[1];
  const float* test_latent = (const float*)d_in[2];
  const float* W = (const float*)d_in[3];
  const float* b = (const float*)d_in[4];
  float* out = (float*)d_out;

  char* ws = (char*)d_ws;
  const size_t REC = 8388608;          // 8 MB each
  const size_t DIST = 134217728;       // 128 MB
  const size_t NEED_FAST = 2 * REC + DIST + 32768;

  float* rec_test = (float*)(ws);
  float* rec_train = (float*)(ws + REC);

  linear_kernel<<<dim3(N / 8, 2), 256, 0, stream>>>(
      test_latent, train_latent, W, b, rec_test, rec_train);

  if (ws_size >= NEED_FAST) {
    float* dist = (float*)(ws + 2 * REC);
    float* scores = (float*)(ws + 2 * REC + DIST);
    dist_kernel<<<dim3(N / DTI, N / DTJ, 2), 256, 0, stream>>>(
        rec_test, gt_vals, rec_train, dist);
    row_topk_kernel<<<2 * N, 256, 0, stream>>>(dist, scores);
    loss_kernel<<<1, 256, 0, stream>>>(scores, out);
  } else {
    float* cand = (float*)(ws + 2 * REC);                 // 8 MB
    float* scores = (float*)(ws + 2 * REC + 8388608);     // 32 KB
    dist_topk_kernel<<<dim3(N / TI, PARTS, 2), 256, 0, stream>>>(
        rec_test, gt_vals, rec_train, cand);
    merge_kernel<<<(2 * N) / 256, 256, 0, stream>>>(cand, scores);
    loss_kernel<<<1, 256, 0, stream>>>(scores, out);
  }
}

// Round 7
// 734.548 us; speedup vs baseline: 10.8224x; 1.0749x over previous
//
#include <hip/hip_runtime.h>
#include <math.h>

#define N 4096
#define D 512
#define L 128

// ---------------- fast path (needs ~144 MB ws) ----------------
#define DTI 128
#define DTJ 128
#define DKD 16            // dbuf chunk; 2 buffers = same 35328 B as R6's KD=32
#define NCH (D / DKD)     // 32 chunks
#define DAS 132           // A LDS stride
#define DBS 144           // B LDS stride; col swizzle j + 4*(j>>5) keeps 16B align
#define BUF_FLOATS (DKD * DAS + DKD * DBS)   // 4416

// ---------------- fallback path (R3, ~25 MB ws) ----------------
#define PARTS 16
#define PARTJ (N / PARTS)
#define TI 128
#define TJ 64
#define KD 32
#define AS_STRIDE (TI + 4)
#define BS_STRIDE (TJ + 4)
#define DS_STRIDE (TJ + 4)
#define SMEM_FLOATS (TI * DS_STRIDE)

// acc += |t| in exactly one VOP3 instr (abs input modifier).
#define ACC_ABS(accv, t) \
  asm("v_add_f32 %0, %0, abs(%1)" : "+v"(accv) : "v"(t))

// Insert v into ascending sorted tk[0..15], dropping the old max.
__device__ __forceinline__ void topk_insert(float (&tk)[16], float v) {
  float x = v;
#pragma unroll
  for (int k = 0; k < 16; ++k) {
    float lo = fminf(x, tk[k]);
    float hi = fmaxf(x, tk[k]);
    tk[k] = lo;
    x = hi;
  }
}

// rec = latent @ W + b ; grid (N/8, 2), block 256.
__global__ __launch_bounds__(256) void linear_kernel(
    const float* __restrict__ lat_test, const float* __restrict__ lat_train,
    const float* __restrict__ W, const float* __restrict__ bias,
    float* __restrict__ rec_test, float* __restrict__ rec_train) {
  const float* __restrict__ lat = blockIdx.y ? lat_train : lat_test;
  float* __restrict__ out = blockIdx.y ? rec_train : rec_test;
  const int r0 = blockIdx.x * 8;
  const int t = threadIdx.x;

  __shared__ float ls[8 * L];
  {
    float4 v = *(const float4*)(lat + (size_t)r0 * L + t * 4);
    *(float4*)&ls[t * 4] = v;
  }
  __syncthreads();

  float acc[8][2];
#pragma unroll
  for (int r = 0; r < 8; ++r) { acc[r][0] = 0.f; acc[r][1] = 0.f; }

#pragma unroll 4
  for (int l = 0; l < L; ++l) {
    float w0 = W[l * D + t];
    float w1 = W[l * D + t + 256];
#pragma unroll
    for (int r = 0; r < 8; ++r) {
      float x = ls[r * L + l];
      acc[r][0] = fmaf(x, w0, acc[r][0]);
      acc[r][1] = fmaf(x, w1, acc[r][1]);
    }
  }
  float b0 = bias[t], b1 = bias[t + 256];
#pragma unroll
  for (int r = 0; r < 8; ++r) {
    out[(size_t)(r0 + r) * D + t] = acc[r][0] + b0;
    out[(size_t)(r0 + r) * D + t + 256] = acc[r][1] + b1;
  }
}

// ============ FAST PATH ============
// L1 cdist, 128x128 tile, 8x8/thread, software-pipelined LDS double-buffer:
// prefetch chunk k+1 into regs BEFORE computing chunk k, store to alt buffer
// after — one barrier per chunk, no vmcnt drain at the barrier.
__global__ __launch_bounds__(256) __attribute__((amdgpu_waves_per_eu(4, 4)))
void dist_kernel(const float* __restrict__ Arec, const float* __restrict__ Bgt,
                 const float* __restrict__ Btr, float* __restrict__ dist) {
  const int i0 = blockIdx.x * DTI;
  const int j0 = blockIdx.y * DTJ;
  const int mat = blockIdx.z;
  const float* __restrict__ B = mat ? Btr : Bgt;
  float* __restrict__ out = dist + (size_t)mat * N * N;

  __shared__ float smem[2][BUF_FLOATS];  // 35328 B -> 4 blocks/CU

  const int tid = threadIdx.x;
  const int tx = tid & 15;
  const int ty = tid >> 4;
  const int aoff = 8 * ty;
  const int boff = 8 * tx + 4 * (tx >> 2);  // swizzled column base

  // staging map: chunk = 128 rows x 16 d = 512 float4 per array, 2/thread each
  const int r0 = tid >> 2;        // 0..63
  const int r1 = r0 + 64;         // 64..127
  const int c4 = tid & 3;         // float4 index within 16-d chunk
  const int jw0 = r0 + 4 * (r0 >> 5);  // swizzled B columns
  const int jw1 = r1 + 4 * (r1 >> 5);
  const float* apA0 = Arec + (size_t)(i0 + r0) * D + c4 * 4;
  const float* apA1 = Arec + (size_t)(i0 + r1) * D + c4 * 4;
  const float* bp0 = B + (size_t)(j0 + r0) * D + c4 * 4;
  const float* bp1 = B + (size_t)(j0 + r1) * D + c4 * 4;

  float acc[8][8];
#pragma unroll
  for (int r = 0; r < 8; ++r)
#pragma unroll
    for (int c = 0; c < 8; ++c) acc[r][c] = 0.f;

  // prologue: load chunk 0 and store into buffer 0
  float4 va0 = *(const float4*)(apA0);
  float4 va1 = *(const float4*)(apA1);
  float4 vb0 = *(const float4*)(bp0);
  float4 vb1 = *(const float4*)(bp1);
  {
    float* As = smem[0];
    float* Bs = As + DKD * DAS;
    As[(4 * c4 + 0) * DAS + r0] = va0.x;
    As[(4 * c4 + 1) * DAS + r0] = va0.y;
    As[(4 * c4 + 2) * DAS + r0] = va0.z;
    As[(4 * c4 + 3) * DAS + r0] = va0.w;
    As[(4 * c4 + 0) * DAS + r1] = va1.x;
    As[(4 * c4 + 1) * DAS + r1] = va1.y;
    As[(4 * c4 + 2) * DAS + r1] = va1.z;
    As[(4 * c4 + 3) * DAS + r1] = va1.w;
    Bs[(4 * c4 + 0) * DBS + jw0] = vb0.x;
    Bs[(4 * c4 + 1) * DBS + jw0] = vb0.y;
    Bs[(4 * c4 + 2) * DBS + jw0] = vb0.z;
    Bs[(4 * c4 + 3) * DBS + jw0] = vb0.w;
    Bs[(4 * c4 + 0) * DBS + jw1] = vb1.x;
    Bs[(4 * c4 + 1) * DBS + jw1] = vb1.y;
    Bs[(4 * c4 + 2) * DBS + jw1] = vb1.z;
    Bs[(4 * c4 + 3) * DBS + jw1] = vb1.w;
  }

#pragma unroll 1
  for (int chunk = 0; chunk < NCH; ++chunk) {
    __syncthreads();  // buf[chunk&1] fully staged for everyone
    // prefetch chunk+1 into regs (latency covered by 16-d compute below)
    if (chunk + 1 < NCH) {
      const int off = (chunk + 1) * DKD;
      va0 = *(const float4*)(apA0 + off);
      va1 = *(const float4*)(apA1 + off);
      vb0 = *(const float4*)(bp0 + off);
      vb1 = *(const float4*)(bp1 + off);
    }

    const float* As = smem[chunk & 1];
    const float* Bs = As + DKD * DAS;
#pragma unroll 4
    for (int d = 0; d < DKD; ++d) {
      float4 a0 = *(const float4*)&As[d * DAS + aoff];
      float4 a1 = *(const float4*)&As[d * DAS + aoff + 4];
      float4 b0 = *(const float4*)&Bs[d * DBS + boff];
      float4 b1 = *(const float4*)&Bs[d * DBS + boff + 4];
#define ROWC(r, av)                                       \
  {                                                       \
    float t0 = av - b0.x; ACC_ABS(acc[r][0], t0);         \
    float t1 = av - b0.y; ACC_ABS(acc[r][1], t1);         \
    float t2 = av - b0.z; ACC_ABS(acc[r][2], t2);         \
    float t3 = av - b0.w; ACC_ABS(acc[r][3], t3);         \
    float t4 = av - b1.x; ACC_ABS(acc[r][4], t4);         \
    float t5 = av - b1.y; ACC_ABS(acc[r][5], t5);         \
    float t6 = av - b1.z; ACC_ABS(acc[r][6], t6);         \
    float t7 = av - b1.w; ACC_ABS(acc[r][7], t7);         \
  }
      ROWC(0, a0.x) ROWC(1, a0.y) ROWC(2, a0.z) ROWC(3, a0.w)
      ROWC(4, a1.x) ROWC(5, a1.y) ROWC(6, a1.z) ROWC(7, a1.w)
#undef ROWC
    }

    // store prefetched regs into the other buffer (its last readers were in
    // the previous iteration's compute, separated by this iter's barrier)
    if (chunk + 1 < NCH) {
      float* Asw = smem[(chunk + 1) & 1];
      float* Bsw = Asw + DKD * DAS;
      Asw[(4 * c4 + 0) * DAS + r0] = va0.x;
      Asw[(4 * c4 + 1) * DAS + r0] = va0.y;
      Asw[(4 * c4 + 2) * DAS + r0] = va0.z;
      Asw[(4 * c4 + 3) * DAS + r0] = va0.w;
      Asw[(4 * c4 + 0) * DAS + r1] = va1.x;
      Asw[(4 * c4 + 1) * DAS + r1] = va1.y;
      Asw[(4 * c4 + 2) * DAS + r1] = va1.z;
      Asw[(4 * c4 + 3) * DAS + r1] = va1.w;
      Bsw[(4 * c4 + 0) * DBS + jw0] = vb0.x;
      Bsw[(4 * c4 + 1) * DBS + jw0] = vb0.y;
      Bsw[(4 * c4 + 2) * DBS + jw0] = vb0.z;
      Bsw[(4 * c4 + 3) * DBS + jw0] = vb0.w;
      Bsw[(4 * c4 + 0) * DBS + jw1] = vb1.x;
      Bsw[(4 * c4 + 1) * DBS + jw1] = vb1.y;
      Bsw[(4 * c4 + 2) * DBS + jw1] = vb1.z;
      Bsw[(4 * c4 + 3) * DBS + jw1] = vb1.w;
    }
  }

#pragma unroll
  for (int r = 0; r < 8; ++r) {
    float* dst = out + (size_t)(i0 + 8 * ty + r) * N + j0 + 8 * tx;
    *(float4*)dst = make_float4(acc[r][0], acc[r][1], acc[r][2], acc[r][3]);
    *(float4*)(dst + 4) = make_float4(acc[r][4], acc[r][5], acc[r][6], acc[r][7]);
  }
}

// One WAVE per row (4 rows per 256-block, grid 2N/4): insert-filtered scan of
// 64 elems/lane, then 6 shfl_xor bitonic merge levels. No LDS, no barriers.
__global__ __launch_bounds__(256) void row_topk_kernel(
    const float* __restrict__ dist, float* __restrict__ scores) {
  const int wave = threadIdx.x >> 6;
  const int lane = threadIdx.x & 63;
  const int row = blockIdx.x * 4 + wave;
  const float* __restrict__ p = dist + (size_t)row * N;

  float tk[16];
#pragma unroll
  for (int k = 0; k < 16; ++k) tk[k] = 3.0e38f;

#pragma unroll 1
  for (int q = 0; q < 16; ++q) {  // each q: wave reads 1 KB contiguous
    float4 v = *(const float4*)(p + q * 256 + lane * 4);
    if (v.x < tk[15]) topk_insert(tk, v.x);
    if (v.y < tk[15]) topk_insert(tk, v.y);
    if (v.z < tk[15]) topk_insert(tk, v.z);
    if (v.w < tk[15]) topk_insert(tk, v.w);
  }

  // recursive-doubling merge: after level m, lanes in each 2m-group identical
#pragma unroll
  for (int m = 1; m < 64; m <<= 1) {
    float oth[16];
#pragma unroll
    for (int k = 0; k < 16; ++k) oth[k] = __shfl_xor(tk[k], m, 64);
    // half-cleaner: lowest 16 of union, result is bitonic
    float lo[16];
#pragma unroll
    for (int k = 0; k < 16; ++k) lo[k] = fminf(tk[k], oth[15 - k]);
    // bitonic sort of a bitonic 16-seq: stages 8,4,2,1 (constant-indexed)
#pragma unroll
    for (int dlt = 8; dlt >= 1; dlt >>= 1) {
#pragma unroll
      for (int i = 0; i < 16; ++i) {
        if ((i & dlt) == 0 && (i + dlt) < 16) {
          float a = lo[i], b = lo[i + dlt];
          lo[i] = fminf(a, b);
          lo[i + dlt] = fmaxf(a, b);
        }
      }
    }
#pragma unroll
    for (int k = 0; k < 16; ++k) tk[k] = lo[k];
  }

  if (lane == 0) {
    float s = 0.f;
#pragma unroll
    for (int k = 0; k < 16; ++k) s += 1.0f / tk[k];
    scores[row] = s * (1.0f / 16.0f);
  }
}

// ============ FALLBACK PATH (R3, proven) ============
__global__ __launch_bounds__(256) void dist_topk_kernel(
    const float* __restrict__ Arec, const float* __restrict__ Bgt,
    const float* __restrict__ Btr, float* __restrict__ cand) {
  const int itile = blockIdx.x;
  const int part = blockIdx.y;
  const int mat = blockIdx.z;
  const float* __restrict__ B = mat ? Btr : Bgt;
  const int i0 = itile * TI;
  const int jbase = part * PARTJ;

  __shared__ float smem[SMEM_FLOATS];
  float* As = smem;
  float* Bs = smem + KD * AS_STRIDE;
  float* distS = smem;

  const int tid = threadIdx.x;
  const int tx = tid & 15;
  const int ty = tid >> 4;
  const int srow = tid >> 1;
  const int shalf = tid & 1;
  const int scol = shalf * 32;

  float tk[16];
#pragma unroll
  for (int k = 0; k < 16; ++k) tk[k] = 3.0e38f;

  for (int jc = 0; jc < PARTJ; jc += TJ) {
    float acc[8][4];
#pragma unroll
    for (int r = 0; r < 8; ++r)
#pragma unroll
      for (int c = 0; c < 4; ++c) acc[r][c] = 0.f;

    for (int d0 = 0; d0 < D; d0 += KD) {
      __syncthreads();
#pragma unroll
      for (int s = 0; s < 4; ++s) {
        int f4 = tid + s * 256;
        int r = f4 >> 3;
        int c4 = f4 & 7;
        float4 v = *(const float4*)(Arec + (size_t)(i0 + r) * D + d0 + c4 * 4);
        As[(4 * c4 + 0) * AS_STRIDE + r] = v.x;
        As[(4 * c4 + 1) * AS_STRIDE + r] = v.y;
        As[(4 * c4 + 2) * AS_STRIDE + r] = v.z;
        As[(4 * c4 + 3) * AS_STRIDE + r] = v.w;
      }
#pragma unroll
      for (int s = 0; s < 2; ++s) {
        int f4 = tid + s * 256;
        int r = f4 >> 3;
        int c4 = f4 & 7;
        float4 v = *(const float4*)(B + (size_t)(jbase + jc + r) * D + d0 + c4 * 4);
        Bs[(4 * c4 + 0) * BS_STRIDE + r] = v.x;
        Bs[(4 * c4 + 1) * BS_STRIDE + r] = v.y;
        Bs[(4 * c4 + 2) * BS_STRIDE + r] = v.z;
        Bs[(4 * c4 + 3) * BS_STRIDE + r] = v.w;
      }
      __syncthreads();

#pragma unroll
      for (int d = 0; d < KD; ++d) {
        float4 a0 = *(const float4*)&As[d * AS_STRIDE + 8 * ty];
        float4 a1 = *(const float4*)&As[d * AS_STRIDE + 8 * ty + 4];
        float4 bv4 = *(const float4*)&Bs[d * BS_STRIDE + 4 * tx];
        float av[8] = {a0.x, a0.y, a0.z, a0.w, a1.x, a1.y, a1.z, a1.w};
        float bv[4] = {bv4.x, bv4.y, bv4.z, bv4.w};
#pragma unroll
        for (int r = 0; r < 8; ++r)
#pragma unroll
          for (int c = 0; c < 4; ++c) acc[r][c] += __builtin_fabsf(av[r] - bv[c]);
      }
    }

    __syncthreads();
#pragma unroll
    for (int r = 0; r < 8; ++r)
      *(float4*)&distS[(8 * ty + r) * DS_STRIDE + 4 * tx] =
          make_float4(acc[r][0], acc[r][1], acc[r][2], acc[r][3]);
    __syncthreads();

#pragma unroll 1
    for (int j4 = 0; j4 < 8; ++j4) {
      float4 v = *(const float4*)&distS[srow * DS_STRIDE + scol + j4 * 4];
      if (v.x < tk[15]) topk_insert(tk, v.x);
      if (v.y < tk[15]) topk_insert(tk, v.y);
      if (v.z < tk[15]) topk_insert(tk, v.z);
      if (v.w < tk[15]) topk_insert(tk, v.w);
    }
  }

  __syncthreads();
  float* mergeS = smem;
#pragma unroll
  for (int k4 = 0; k4 < 4; ++k4)
    *(float4*)&mergeS[srow * 32 + shalf * 16 + k4 * 4] =
        make_float4(tk[k4 * 4], tk[k4 * 4 + 1], tk[k4 * 4 + 2], tk[k4 * 4 + 3]);
  __syncthreads();

  if (tid < TI) {
    const float* LA = &mergeS[tid * 32];
    const float* LB = LA + 16;
    const int row = i0 + tid;
    float* dst = cand + ((size_t)((mat * PARTS + part) * N) + row) * 16;
    int ia = 0, ib = 0;
#pragma unroll 1
    for (int k = 0; k < 16; ++k) {
      float a = LA[ia < 16 ? ia : 15];
      float b = LB[ib < 16 ? ib : 15];
      bool takeA = (ib >= 16) || (ia < 16 && a <= b);
      dst[k] = takeA ? a : b;
      ia += takeA ? 1 : 0;
      ib += takeA ? 0 : 1;
    }
  }
}

__global__ __launch_bounds__(256) void merge_kernel(
    const float* __restrict__ cand, float* __restrict__ scores) {
  const int gid = blockIdx.x * 256 + threadIdx.x;
  if (gid >= 2 * N) return;
  const int m = gid >> 12;
  const int row = gid & (N - 1);

  float tk[16];
#pragma unroll
  for (int k = 0; k < 16; ++k) tk[k] = 3.0e38f;

  for (int p = 0; p < PARTS; ++p) {
    const float* lp = cand + ((size_t)((m * PARTS + p) * N) + row) * 16;
#pragma unroll 1
    for (int k = 0; k < 16; ++k) {
      float v = lp[k];
      if (v >= tk[15]) break;
      topk_insert(tk, v);
    }
  }
  float s = 0.f;
#pragma unroll
  for (int k = 0; k < 16; ++k) s += 1.0f / tk[k];
  scores[(size_t)m * N + row] = s * (1.0f / 16.0f);
}

// losses = relu(neg - pos); huber(delta=1) vs 0; mean. Single block.
__global__ __launch_bounds__(256) void loss_kernel(
    const float* __restrict__ scores, float* __restrict__ out) {
  const int tid = threadIdx.x;
  float s = 0.f;
  for (int i = tid; i < N; i += 256) {
    float l = scores[N + i] - scores[i];
    l = fmaxf(l, 0.f);
    s += (l <= 1.f) ? 0.5f * l * l : (l - 0.5f);
  }
#pragma unroll
  for (int off = 32; off > 0; off >>= 1) s += __shfl_down(s, off, 64);
  __shared__ float ws[4];
  if ((tid & 63) == 0) ws[tid >> 6] = s;
  __syncthreads();
  if (tid == 0) {
    float t = ws[0] + ws[1] + ws[2] + ws[3];
    out[0] = t * (1.0f / (float)N);
  }
}

extern "C" void kernel_launch(void* const* d_in, const int* in_sizes, int n_in,
                              void* d_out, int out_size, void* d_ws, size_t ws_size,
                              hipStream_t stream) {
  const float* gt_vals = (const float*)d_in[0];
  const float* train_latent = (const float*)d_in[1];
  const float* test_latent = (const float*)d_in[2];
  const float* W = (const float*)d_in[3];
  const float* b = (const float*)d_in[4];
  float* out = (float*)d_out;

  char* ws = (char*)d_ws;
  const size_t REC = 8388608;          // 8 MB each
  const size_t DIST = 134217728;       // 128 MB
  const size_t NEED_FAST = 2 * REC + DIST + 32768;

  float* rec_test = (float*)(ws);
  float* rec_train = (float*)(ws + REC);

  linear_kernel<<<dim3(N / 8, 2), 256, 0, stream>>>(
      test_latent, train_latent, W, b, rec_test, rec_train);

  if (ws_size >= NEED_FAST) {
    float* dist = (float*)(ws + 2 * REC);
    float* scores = (float*)(ws + 2 * REC + DIST);
    dist_kernel<<<dim3(N / DTI, N / DTJ, 2), 256, 0, stream>>>(
        rec_test, gt_vals, rec_train, dist);
    row_topk_kernel<<<(2 * N) / 4, 256, 0, stream>>>(dist, scores);
    loss_kernel<<<1, 256, 0, stream>>>(scores, out);
  } else {
    float* cand = (float*)(ws + 2 * REC);                 // 8 MB
    float* scores = (float*)(ws + 2 * REC + 8388608);     // 32 KB
    dist_topk_kernel<<<dim3(N / TI, PARTS, 2), 256, 0, stream>>>(
        rec_test, gt_vals, rec_train, cand);
    merge_kernel<<<(2 * N) / 256, 256, 0, stream>>>(cand, scores);
    loss_kernel<<<1, 256, 0, stream>>>(scores, out);
  }
}